// Round 11
// baseline (333.342 us; speedup 1.0000x reference)
//
#include <hip/hip_runtime.h>

// GraphSAGE 4-layer encoder, N=100000 nodes, d=64, E=1.6M edges.
//   1. CSR build via 2-level bucket sort (packed bdata; N <= 131072).
//   2. Per layer: MFMA GEMM (f16 in, f32 acc): P = h@Wl (f16), R = h@Wr+bl
//      (f16); pair-gather: h_out = act(invdeg*sum P[nbr] + R) [+res] [L2n].
// R10->R11 (bisection): R10 fused pair-gather+GEMM FAILED (absmax 0.216).
// This round: R9's proven separate-kernel skeleton, ONLY the gather replaced
// by the standalone pair version (lanes 0-31 node A, 32-63 node B; one csr
// load + 8 P-loads in flight per 16-edge batch per node; 4-shfl epilogue).

#include <hip/hip_bf16.h>

static inline size_t al256(size_t x) { return (x + 255) & ~(size_t)255; }

#define EPB 8192

typedef _Float16 f16x8 __attribute__((ext_vector_type(8)));
typedef _Float16 h2v __attribute__((ext_vector_type(2)));
typedef float f32x4 __attribute__((ext_vector_type(4)));
union HU { unsigned u32; h2v h; };
union Q4 { uint2 u; _Float16 hh[4]; };

// ---- edge dtype detection (int32 vs int64), sampled.
__global__ void k_detect(const unsigned int* __restrict__ raw, int E, int* __restrict__ flag) {
  int nz = 0;
#pragma unroll
  for (int k = 0; k < 64; ++k) {
    int i = threadIdx.x + (k << 8);
    if (i < E && raw[2 * (size_t)i + 1] != 0u) nz = 1;
  }
  unsigned long long b = __ballot(nz != 0);
  if ((threadIdx.x & 63) == 0 && b) atomicOr(flag, 1);
}

__global__ __launch_bounds__(256) void k_bcount(const unsigned int* __restrict__ raw, int E,
                                                int span, const int* __restrict__ flag,
                                                int* __restrict__ bucketCount) {
  __shared__ int lh[256];
  int t = threadIdx.x;
  lh[t] = 0;
  __syncthreads();
  int f = *flag;
  int base = blockIdx.x * EPB;
#pragma unroll 4
  for (int k = 0; k < EPB / 256; ++k) {
    int i = base + k * 256 + t;
    if (i < E) {
      int dst = f ? (int)raw[E + i] : (int)raw[2 * (size_t)(E + i)];
      atomicAdd(&lh[dst / span], 1);
    }
  }
  __syncthreads();
  int c = lh[t];
  if (c) atomicAdd(&bucketCount[t], c);
}

__global__ void k_bscan(const int* __restrict__ bucketCount, int* __restrict__ boff,
                        int* __restrict__ cursorB, int* __restrict__ rs, int N, int E) {
  __shared__ int sa[256], sb[256];
  int t = threadIdx.x;
  int v = bucketCount[t];
  sa[t] = v;
  __syncthreads();
  int* s = sa;
  int* d = sb;
  for (int off = 1; off < 256; off <<= 1) {
    d[t] = s[t] + (t >= off ? s[t - off] : 0);
    __syncthreads();
    int* tmp = s; s = d; d = tmp;
  }
  int inc = s[t];
  int ex = inc - v;
  boff[t] = ex;
  cursorB[t] = ex;
  if (t == 255) boff[256] = inc;
  if (t == 0) rs[N] = E;
}

__global__ __launch_bounds__(256) void k_bscatter(const unsigned int* __restrict__ raw, int E,
                                                  int span, const int* __restrict__ flag,
                                                  int* __restrict__ cursorB,
                                                  unsigned* __restrict__ bdata) {
  __shared__ int lh[256], lcur[256], gbase[256];
  int t = threadIdx.x;
  lh[t] = 0;
  lcur[t] = 0;
  __syncthreads();
  int f = *flag;
  int base = blockIdx.x * EPB;
#pragma unroll 4
  for (int k = 0; k < EPB / 256; ++k) {
    int i = base + k * 256 + t;
    if (i < E) {
      int dst = f ? (int)raw[E + i] : (int)raw[2 * (size_t)(E + i)];
      atomicAdd(&lh[dst / span], 1);
    }
  }
  __syncthreads();
  int c = lh[t];
  gbase[t] = c ? atomicAdd(&cursorB[t], c) : 0;
  __syncthreads();
#pragma unroll 4
  for (int k = 0; k < EPB / 256; ++k) {
    int i = base + k * 256 + t;
    if (i < E) {
      int s_, d_;
      if (f) { s_ = (int)raw[i]; d_ = (int)raw[E + i]; }
      else   { s_ = (int)raw[2 * (size_t)i]; d_ = (int)raw[2 * (size_t)(E + i)]; }
      int b = d_ / span;
      int pos = atomicAdd(&lcur[b], 1);
      bdata[(size_t)gbase[b] + pos] = ((unsigned)(d_ - b * span) << 17) | (unsigned)s_;
    }
  }
}

__global__ __launch_bounds__(256) void k_bbuild(const unsigned* __restrict__ bdata,
                                                const int* __restrict__ boff, int span, int N,
                                                int* __restrict__ csr, int* __restrict__ rs,
                                                float* __restrict__ invdeg) {
  __shared__ int cnt[512], sa[512], sb[512], cur[512];
  int b = blockIdx.x;
  int t = threadIdx.x;
  int node0 = b * span;
  int beg = boff[b], end = boff[b + 1];
  cnt[t] = 0;
  cnt[t + 256] = 0;
  __syncthreads();
  for (int i = beg + t; i < end; i += 256) {
    atomicAdd(&cnt[bdata[i] >> 17], 1);
  }
  __syncthreads();
  sa[t] = cnt[t];
  sa[t + 256] = cnt[t + 256];
  __syncthreads();
  int* s = sa;
  int* d = sb;
  for (int off = 1; off < 512; off <<= 1) {
    d[t] = s[t] + (t >= off ? s[t - off] : 0);
    int i2 = t + 256;
    d[i2] = s[i2] + (i2 >= off ? s[i2 - off] : 0);
    __syncthreads();
    int* tmp = s; s = d; d = tmp;
  }
  int ex0 = s[t] - cnt[t];
  int ex1 = s[t + 256] - cnt[t + 256];
  cur[t] = ex0;
  cur[t + 256] = ex1;
  if (t < span) {
    int node = node0 + t;
    if (node < N) {
      rs[node] = beg + ex0;
      invdeg[node] = 1.0f / fmaxf((float)cnt[t], 1.0f);
    }
  }
  int t2 = t + 256;
  if (t2 < span) {
    int node = node0 + t2;
    if (node < N) {
      rs[node] = beg + ex1;
      invdeg[node] = 1.0f / fmaxf((float)cnt[t2], 1.0f);
    }
  }
  __syncthreads();
  for (int i = beg + t; i < end; i += 256) {
    unsigned p = bdata[i];
    int pos = atomicAdd(&cur[p >> 17], 1);
    csr[beg + pos] = (int)(p & 0x1FFFFu);
  }
}

// ---- MFMA GEMM: P(f16) = h @ Wl ; R(f16) = h @ Wr + bl. (R9-proven)
// IT=0: h f32; IT=1: h f16.
template <int IT>
__global__ __launch_bounds__(256) void k_gemm(
    const void* __restrict__ hv_, const float* __restrict__ Wl,
    const float* __restrict__ Wr, const float* __restrict__ bl,
    unsigned short* __restrict__ Pf, unsigned short* __restrict__ R16, int n) {
  __shared__ uint4 hAu[512];
  char* hAraw = (char*)hAu;
  int t = threadIdx.x;
  int n0 = blockIdx.x * 64;
  int w = t >> 6;
  int l = t & 63;
  int lo16 = l & 15;
  int g = l >> 4;

#pragma unroll
  for (int c = 0; c < 4; ++c) {
    int idx = t + c * 256;
    int row = idx >> 4;
    int fc = idx & 15;
    int nn = n0 + row;
    uint2 u = make_uint2(0u, 0u);
    if (nn < n) {
      if (IT == 0) {
        const float* h = (const float*)hv_;
        float4 hv = *(const float4*)&h[(size_t)nn * 64 + fc * 4];
        union { _Float16 p[4]; uint2 u; } cv;
        cv.p[0] = (_Float16)hv.x; cv.p[1] = (_Float16)hv.y;
        cv.p[2] = (_Float16)hv.z; cv.p[3] = (_Float16)hv.w;
        u = cv.u;
      } else {
        u = *(const uint2*)((const char*)hv_ + (size_t)nn * 128 + fc * 8);
      }
    }
    int byte = (row * 128 + fc * 8) ^ ((row & 7) << 4);
    *(uint2*)(hAraw + byte) = u;
  }

  const float* Wsel = (w < 2) ? Wl : Wr;
  int colbase = (w & 1) * 32;
  f16x8 bfr[2][2];
#pragma unroll
  for (int nf = 0; nf < 2; ++nf) {
    int j = colbase + nf * 16 + lo16;
#pragma unroll
    for (int kk = 0; kk < 2; ++kk) {
      int k0 = kk * 32 + g * 8;
      f16x8 bb;
#pragma unroll
      for (int s = 0; s < 8; ++s) bb[s] = (_Float16)Wsel[(k0 + s) * 64 + j];
      bfr[nf][kk] = bb;
    }
  }
  __syncthreads();

  f32x4 acc[4][2];
#pragma unroll
  for (int mf = 0; mf < 4; ++mf)
#pragma unroll
    for (int nf = 0; nf < 2; ++nf) acc[mf][nf] = (f32x4){0.f, 0.f, 0.f, 0.f};

#pragma unroll
  for (int mf = 0; mf < 4; ++mf) {
    int row = mf * 16 + lo16;
    int swz = (row & 7) << 4;
    f16x8 av0 = *(const f16x8*)(hAraw + row * 128 + ((g * 16) ^ swz));
    f16x8 av1 = *(const f16x8*)(hAraw + row * 128 + ((64 + g * 16) ^ swz));
#pragma unroll
    for (int nf = 0; nf < 2; ++nf) {
      acc[mf][nf] = __builtin_amdgcn_mfma_f32_16x16x32_f16(av0, bfr[nf][0], acc[mf][nf], 0, 0, 0);
      acc[mf][nf] = __builtin_amdgcn_mfma_f32_16x16x32_f16(av1, bfr[nf][1], acc[mf][nf], 0, 0, 0);
    }
  }

#pragma unroll
  for (int nf = 0; nf < 2; ++nf) {
    int col = colbase + nf * 16 + lo16;
    float bv = (w >= 2) ? bl[col] : 0.f;
#pragma unroll
    for (int mf = 0; mf < 4; ++mf) {
#pragma unroll
      for (int r = 0; r < 4; ++r) {
        int grow = n0 + mf * 16 + g * 4 + r;
        if (grow < n) {
          float v = acc[mf][nf][r];
          union { _Float16 hh; unsigned short us; } cv;
          if (w < 2) {
            cv.hh = (_Float16)v;
            Pf[(size_t)grow * 64 + col] = cv.us;
          } else {
            cv.hh = (_Float16)(v + bv);
            R16[(size_t)grow * 64 + col] = cv.us;
          }
        }
      }
    }
  }
}

// ---- standalone PAIR gather (the R10 logic under bisection test).
// Block = 4 waves x 2 nodes = 8 nodes. Lane l: half=l>>5 selects node,
// q=l&15 dim-quad, g2=(l>>4)&1 edge parity. MODE 0 relu->f16; 1
// relu+res->f16; 2 plain+L2norm->f32.
template <int MODE>
__global__ __launch_bounds__(256) void k_gatherP(
    const uint2* __restrict__ P2, const unsigned short* __restrict__ R16,
    const unsigned short* __restrict__ hres, const int* __restrict__ csr,
    const int* __restrict__ rs, const float* __restrict__ invdeg,
    void* __restrict__ hout, int n, int E) {
  int t = threadIdx.x;
  int w = t >> 6;
  int l = t & 63;
  int half = l >> 5;
  int q = l & 15;
  int g2 = (l >> 4) & 1;
  int v = blockIdx.x * 8 + w * 2 + half;
  int bH = rs[v < n ? v : n];
  int eH = rs[(v + 1) < n ? (v + 1) : n];  // v>=n -> both rs[n] -> rH=0
  int rH = eH - bH;
  float idg = 1.f;
  Q4 rq; rq.u = make_uint2(0u, 0u);
  Q4 hq; hq.u = make_uint2(0u, 0u);
  if ((l & 16) == 0 && v < n) {
    idg = invdeg[v];
    rq.u = *(const uint2*)((const char*)R16 + (size_t)v * 128 + q * 8);
    if (MODE == 1) hq.u = *(const uint2*)((const char*)hres + (size_t)v * 128 + q * 8);
  }
  float s0 = 0.f, s1 = 0.f, s2 = 0.f, s3 = 0.f;
  int rOther = __shfl_xor(rH, 32, 64);
  int maxR = rH > rOther ? rH : rOther;
  int nb = (maxR + 15) >> 4;
  for (int bt = 0; bt < nb; ++bt) {
    int rem = rH - (bt << 4);
    int offc = (rem > 0) ? ((q < rem) ? q : rem - 1) : 0;
    int addr = bH + (bt << 4) + offc;
    addr = (addr < E) ? addr : E - 1;
    int myidx = csr[addr];
    h2v a0 = (h2v)0, a1 = (h2v)0;
    int remMax = maxR - (bt << 4);
#pragma unroll
    for (int tt = 0; tt < 8; ++tt) {
      if (2 * tt >= remMax) break;  // wave-uniform
      int ee = 2 * tt + g2;
      int sel = __shfl(myidx, (half << 5) + ee, 64);
      uint2 u = P2[(unsigned)((sel << 4) + q)];
      bool m = ee < rem;
      HU b0, b1;
      b0.u32 = m ? u.x : 0u;
      b1.u32 = m ? u.y : 0u;
      a0 += b0.h;
      a1 += b1.h;
    }
    s0 += (float)a0[0];
    s1 += (float)a0[1];
    s2 += (float)a1[0];
    s3 += (float)a1[1];
  }
  s0 += __shfl_xor(s0, 16, 64);
  s1 += __shfl_xor(s1, 16, 64);
  s2 += __shfl_xor(s2, 16, 64);
  s3 += __shfl_xor(s3, 16, 64);

  if ((l & 16) == 0 && v < n) {
    float4 o;
    o.x = s0 * idg + (float)rq.hh[0];
    o.y = s1 * idg + (float)rq.hh[1];
    o.z = s2 * idg + (float)rq.hh[2];
    o.w = s3 * idg + (float)rq.hh[3];
    if (MODE == 0) {
      o.x = fmaxf(o.x, 0.f); o.y = fmaxf(o.y, 0.f);
      o.z = fmaxf(o.z, 0.f); o.w = fmaxf(o.w, 0.f);
    } else if (MODE == 1) {
      o.x = fmaxf(o.x, 0.f) + (float)hq.hh[0];
      o.y = fmaxf(o.y, 0.f) + (float)hq.hh[1];
      o.z = fmaxf(o.z, 0.f) + (float)hq.hh[2];
      o.w = fmaxf(o.w, 0.f) + (float)hq.hh[3];
    } else {
      float sq = o.x * o.x + o.y * o.y + o.z * o.z + o.w * o.w;
#pragma unroll
      for (int m = 1; m < 16; m <<= 1) sq += __shfl_xor(sq, m, 64);
      float nrm = fmaxf(sqrtf(sq), 1e-12f);
      o.x /= nrm; o.y /= nrm; o.z /= nrm; o.w /= nrm;
    }
    if (MODE == 2) {
      *(float4*)&((float*)hout)[((size_t)v << 6) + (q << 2)] = o;
    } else {
      Q4 oq;
      oq.hh[0] = (_Float16)o.x; oq.hh[1] = (_Float16)o.y;
      oq.hh[2] = (_Float16)o.z; oq.hh[3] = (_Float16)o.w;
      *(uint2*)((char*)hout + (size_t)v * 128 + q * 8) = oq.u;
    }
  }
}

extern "C" void kernel_launch(void* const* d_in, const int* in_sizes, int n_in,
                              void* d_out, int out_size, void* d_ws, size_t ws_size,
                              hipStream_t stream) {
  const float* x = (const float*)d_in[0];
  const unsigned int* eraw = (const unsigned int*)d_in[1];
  const float* Wl[4] = {(const float*)d_in[2], (const float*)d_in[5],
                        (const float*)d_in[8], (const float*)d_in[11]};
  const float* blv[4] = {(const float*)d_in[3], (const float*)d_in[6],
                         (const float*)d_in[9], (const float*)d_in[12]};
  const float* Wr[4] = {(const float*)d_in[4], (const float*)d_in[7],
                        (const float*)d_in[10], (const float*)d_in[13]};
  const int N = in_sizes[0] / 64;
  const int E = in_sizes[1] / 2;
  const int span = (N + 255) / 256;  // <= 512
  float* out = (float*)d_out;

  char* w = (char*)d_ws;
  size_t off = 0;
  int* flag = (int*)(w + off);        off = al256(off + 4);
  int* bucketCount = (int*)(w + off); off = al256(off + 256 * 4);
  int* boff = (int*)(w + off);        off = al256(off + 257 * 4);
  int* cursorB = (int*)(w + off);     off = al256(off + 256 * 4);
  int* csr = (int*)(w + off);         off = al256(off + (size_t)E * 4);
  float* invdeg = (float*)(w + off);  off = al256(off + (size_t)N * 4);
  int* rs = (int*)(w + off);          off = al256(off + (size_t)(N + 1) * 4);
  unsigned* bdata = (unsigned*)(w + off); off = al256(off + (size_t)E * 4);
  unsigned short* hA = (unsigned short*)(w + off); off = al256(off + (size_t)N * 64 * 2);
  unsigned short* hB = (unsigned short*)(w + off); off = al256(off + (size_t)N * 64 * 2);
  unsigned short* Pf = (unsigned short*)(w + off); off = al256(off + (size_t)N * 64 * 2);
  unsigned short* R16 = (unsigned short*)(w + off); off = al256(off + (size_t)N * 64 * 2);

  hipMemsetAsync(flag, 0, 4, stream);
  hipMemsetAsync(bucketCount, 0, 256 * 4, stream);

  int eb = (E + EPB - 1) / EPB;
  k_detect<<<1, 256, 0, stream>>>(eraw, E, flag);
  k_bcount<<<eb, 256, 0, stream>>>(eraw, E, span, flag, bucketCount);
  k_bscan<<<1, 256, 0, stream>>>(bucketCount, boff, cursorB, rs, N, E);
  k_bscatter<<<eb, 256, 0, stream>>>(eraw, E, span, flag, cursorB, bdata);
  k_bbuild<<<256, 256, 0, stream>>>(bdata, boff, span, N, csr, rs, invdeg);

  int gb = (N + 63) / 64;
  int nb8 = (N + 7) / 8;
  const uint2* P2 = (const uint2*)Pf;
  // Layer 1: x(f32) -> hA (relu, f16)
  k_gemm<0><<<gb, 256, 0, stream>>>(x, Wl[0], Wr[0], blv[0], Pf, R16, N);
  k_gatherP<0><<<nb8, 256, 0, stream>>>(P2, R16, nullptr, csr, rs, invdeg, hA, N, E);
  // Layer 2: hA -> hB (relu + residual hA, f16)
  k_gemm<1><<<gb, 256, 0, stream>>>(hA, Wl[1], Wr[1], blv[1], Pf, R16, N);
  k_gatherP<1><<<nb8, 256, 0, stream>>>(P2, R16, hA, csr, rs, invdeg, hB, N, E);
  // Layer 3: hB -> hA (relu + residual hB, f16)
  k_gemm<1><<<gb, 256, 0, stream>>>(hB, Wl[2], Wr[2], blv[2], Pf, R16, N);
  k_gatherP<1><<<nb8, 256, 0, stream>>>(P2, R16, hB, csr, rs, invdeg, hA, N, E);
  // Layer 4: hA -> out (no act, L2-normalize rows, f32)
  k_gemm<1><<<gb, 256, 0, stream>>>(hA, Wl[3], Wr[3], blv[3], Pf, R16, N);
  k_gatherP<2><<<nb8, 256, 0, stream>>>(P2, R16, nullptr, csr, rs, invdeg, out, N, E);
}